// Round 1
// baseline (3052.695 us; speedup 1.0000x reference)
//
#include <hip/hip_runtime.h>
#include <math.h>

// ---------------------------------------------------------------------------
// AttentiveFP forward, MI355X baseline.
// N=50000 nodes, E=800000 edges, H=128, G=1000 graphs, NL=4, NT=2.
// Strategy: CSR-by-dst + online-softmax conv kernels (wave/node, no atomics),
// f32 tiled GEMM (64x32 tile, K=128), fused GRU (2 GEMMs + gates in one kernel).
// ---------------------------------------------------------------------------

#define WAVE 64

__device__ __forceinline__ float leaky01(float v) { return v > 0.f ? v : 0.01f * v; }
__device__ __forceinline__ float eluf(float v)    { return v > 0.f ? v : (expf(v) - 1.f); }
__device__ __forceinline__ float sigmf(float v)   { return 1.f / (1.f + expf(-v)); }

// ------------------------------ CSR build ----------------------------------

__global__ void k_hist(const int* __restrict__ idx, int* __restrict__ cnt, int n) {
  int i = blockIdx.x * 256 + threadIdx.x;
  if (i < n) atomicAdd(&cnt[idx[i]], 1);
}

__global__ void k_scan1(const int* __restrict__ in, int* __restrict__ out1,
                        int* __restrict__ bsums, int n) {
  __shared__ int s[256];
  int t = threadIdx.x;
  int i = blockIdx.x * 256 + t;
  int v = (i < n) ? in[i] : 0;
  s[t] = v;
  __syncthreads();
  for (int off = 1; off < 256; off <<= 1) {
    int tv = (t >= off) ? s[t - off] : 0;
    __syncthreads();
    s[t] += tv;
    __syncthreads();
  }
  if (i < n) out1[i] = s[t];
  if (t == 255) bsums[blockIdx.x] = s[255];
}

__global__ void k_scan2(int* __restrict__ bsums, int nb) {
  __shared__ int s[256];
  int t = threadIdx.x;
  int v = (t < nb) ? bsums[t] : 0;
  s[t] = v;
  __syncthreads();
  for (int off = 1; off < 256; off <<= 1) {
    int tv = (t >= off) ? s[t - off] : 0;
    __syncthreads();
    s[t] += tv;
    __syncthreads();
  }
  if (t < nb) bsums[t] = s[t];
}

__global__ void k_scan3(int* __restrict__ out1, const int* __restrict__ bsums, int n) {
  int b = blockIdx.x;
  if (b == 0) return;
  int i = b * 256 + threadIdx.x;
  if (i < n) out1[i] += bsums[b - 1];
}

__global__ void k_scatter(const int* __restrict__ ei, const int* __restrict__ off,
                          int* __restrict__ cur, int* __restrict__ csrc,
                          int* __restrict__ ceid, int E) {
  int e = blockIdx.x * 256 + threadIdx.x;
  if (e >= E) return;
  int s = ei[e];          // src row
  int d = ei[E + e];      // dst row
  int pos = off[d] + atomicAdd(&cur[d], 1);
  csrc[pos] = s;
  ceid[pos] = e;
}

// ------------------------------ GEMM (K=128) -------------------------------
// C[M,Nout] = act(A[M,128] @ W + bias). W normal: [128,Nout]; wTrans: [Nout,128].
// BM=64, BN=32, 256 threads, thread tile 4x2 (strided row/col mapping).

__launch_bounds__(256)
__global__ void k_gemm(const float* __restrict__ A, const float* __restrict__ W,
                       const float* __restrict__ bias, float* __restrict__ C,
                       int M, int Nout, int wTrans, int act) {
  __shared__ float As[64][132];
  __shared__ float Bt[32][132];
  int t = threadIdx.x;
  int m0 = blockIdx.x * 64;
  int n0 = blockIdx.y * 32;

  // load A tile: 64 rows x 128 cols = 2048 float4, 8 per thread
  #pragma unroll
  for (int i = 0; i < 8; ++i) {
    int f = t + i * 256;
    int row = f >> 5, kf = f & 31;
    float4 v = make_float4(0.f, 0.f, 0.f, 0.f);
    int gr = m0 + row;
    if (gr < M) v = *(const float4*)(A + (size_t)gr * 128 + kf * 4);
    *(float4*)(&As[row][kf * 4]) = v;
  }
  // load W tile: 32 cols x 128 k = 1024 float4, 4 per thread
  if (wTrans) {
    #pragma unroll
    for (int i = 0; i < 4; ++i) {
      int f = t + i * 256;
      int nr = f >> 5, kf = f & 31;
      float4 v = *(const float4*)(W + (size_t)(n0 + nr) * 128 + kf * 4);
      *(float4*)(&Bt[nr][kf * 4]) = v;
    }
  } else {
    #pragma unroll
    for (int i = 0; i < 4; ++i) {
      int f = t + i * 256;
      int k = f >> 3, nc = f & 7;
      float4 v = *(const float4*)(W + (size_t)k * Nout + n0 + nc * 4);
      Bt[nc * 4 + 0][k] = v.x;
      Bt[nc * 4 + 1][k] = v.y;
      Bt[nc * 4 + 2][k] = v.z;
      Bt[nc * 4 + 3][k] = v.w;
    }
  }
  __syncthreads();

  int g = t >> 4;   // 0..15 row group
  int u = t & 15;   // 0..15 col group
  float acc[4][2] = {};
  for (int k = 0; k < 128; k += 4) {
    float4 a4[4], b4[2];
    #pragma unroll
    for (int i = 0; i < 4; ++i) a4[i] = *(const float4*)(&As[g + 16 * i][k]);
    #pragma unroll
    for (int j = 0; j < 2; ++j) b4[j] = *(const float4*)(&Bt[u + 16 * j][k]);
    #pragma unroll
    for (int i = 0; i < 4; ++i)
      #pragma unroll
      for (int j = 0; j < 2; ++j)
        acc[i][j] += a4[i].x * b4[j].x + a4[i].y * b4[j].y +
                     a4[i].z * b4[j].z + a4[i].w * b4[j].w;
  }

  #pragma unroll
  for (int i = 0; i < 4; ++i) {
    int gr = m0 + g + 16 * i;
    if (gr >= M) continue;
    #pragma unroll
    for (int j = 0; j < 2; ++j) {
      int gc = n0 + u + 16 * j;
      float v = acc[i][j];
      if (bias) v += bias[gc];
      if (act == 1) v = leaky01(v);
      else if (act == 2) v = fmaxf(v, 0.f);
      else if (act == 3) v = eluf(v);
      C[(size_t)gr * Nout + gc] = v;
    }
  }
}

// ------------------------------ matvec (1 or 2 vectors) --------------------

__global__ void k_matvec2(const float* __restrict__ A, const float* __restrict__ v1,
                          const float* __restrict__ v2, float* __restrict__ o1,
                          float* __restrict__ o2, int M) {
  int wid = (blockIdx.x * blockDim.x + threadIdx.x) >> 6;
  int lane = threadIdx.x & 63;
  if (wid >= M) return;
  const float* a = A + (size_t)wid * 128;
  float a0 = a[lane], a1 = a[lane + 64];
  float p1 = a0 * v1[lane] + a1 * v1[lane + 64];
  #pragma unroll
  for (int o = 32; o > 0; o >>= 1) p1 += __shfl_xor(p1, o, 64);
  if (lane == 0) o1[wid] = p1;
  if (v2) {
    float p2 = a0 * v2[lane] + a1 * v2[lane + 64];
    #pragma unroll
    for (int o = 32; o > 0; o >>= 1) p2 += __shfl_xor(p2, o, 64);
    if (lane == 0) o2[wid] = p2;
  }
}

// ------------------------------ GATEConv aggregate -------------------------
// wave per node; online softmax over incoming edges; agg[n] = sum alpha*hj.

__global__ void k_conv_gate(const float* __restrict__ xg, const float* __restrict__ w128,
                            const float* __restrict__ attL, const float* __restrict__ xr,
                            const float* __restrict__ ea, const int* __restrict__ off,
                            const int* __restrict__ csrc, const int* __restrict__ ceid,
                            float* __restrict__ agg, int N) {
  int wid = (blockIdx.x * blockDim.x + threadIdx.x) >> 6;
  if (wid >= N) return;
  int lane = threadIdx.x & 63;
  int j0 = lane * 2;
  float aL0 = attL[j0], aL1 = attL[j0 + 1];
  float w0 = w128[j0], w1 = w128[j0 + 1];
  float xrn = xr[wid];
  float m = -INFINITY, s = 0.f, acc0 = 0.f, acc1 = 0.f;
  int e0 = off[wid], e1 = off[wid + 1];
  for (int e = e0; e < e1; ++e) {
    int src = csrc[e];
    float eav = ea[ceid[e]];
    float2 xv = *(const float2*)(xg + (size_t)src * 128 + j0);
    float h0 = leaky01(xv.x + eav * w0);
    float h1 = leaky01(xv.y + eav * w1);
    float part = h0 * aL0 + h1 * aL1;
    #pragma unroll
    for (int o = 32; o > 0; o >>= 1) part += __shfl_xor(part, o, 64);
    float logit = leaky01(part + xrn);
    float mn = fmaxf(m, logit);
    float sc = expf(m - mn);
    float p = expf(logit - mn);
    s = s * sc + p;
    acc0 = acc0 * sc + p * h0;
    acc1 = acc1 * sc + p * h1;
    m = mn;
  }
  float r = 1.f / (s + 1e-16f);
  float2 res = make_float2(acc0 * r, acc1 * r);
  *(float2*)(agg + (size_t)wid * 128 + j0) = res;
}

// ------------------------------ GATConv ------------------------------------
// hout[n] = elu( (sum alpha*hs[src]) / (s+eps) + bc )

__global__ void k_conv_gat(const float* __restrict__ hs, const float* __restrict__ as_,
                           const float* __restrict__ ad_, const float* __restrict__ bcl,
                           const int* __restrict__ off, const int* __restrict__ csrc,
                           float* __restrict__ hout, int N) {
  int wid = (blockIdx.x * blockDim.x + threadIdx.x) >> 6;
  if (wid >= N) return;
  int lane = threadIdx.x & 63;
  int j0 = lane * 2;
  float adn = ad_[wid];
  float m = -INFINITY, s = 0.f, acc0 = 0.f, acc1 = 0.f;
  int e0 = off[wid], e1 = off[wid + 1];
  for (int e = e0; e < e1; ++e) {
    int src = csrc[e];
    float logit = leaky01(as_[src] + adn);
    float mn = fmaxf(m, logit);
    float sc = expf(m - mn);
    float p = expf(logit - mn);
    float2 hv = *(const float2*)(hs + (size_t)src * 128 + j0);
    s = s * sc + p;
    acc0 = acc0 * sc + p * hv.x;
    acc1 = acc1 * sc + p * hv.y;
    m = mn;
  }
  float r = 1.f / (s + 1e-16f);
  hout[(size_t)wid * 128 + j0]     = eluf(acc0 * r + bcl[j0]);
  hout[(size_t)wid * 128 + j0 + 1] = eluf(acc1 * r + bcl[j0 + 1]);
}

// ------------------------------ graph pooling ------------------------------

__global__ void k_pool(const float* __restrict__ X, const int* __restrict__ goff,
                       float* __restrict__ outb, int G) {
  int wid = (blockIdx.x * blockDim.x + threadIdx.x) >> 6;
  if (wid >= G) return;
  int lane = threadIdx.x & 63;
  int j0 = lane * 2;
  float s0 = 0.f, s1 = 0.f;
  int n0 = goff[wid], n1 = goff[wid + 1];
  for (int n = n0; n < n1; ++n) {
    float2 v = *(const float2*)(X + (size_t)n * 128 + j0);
    s0 += v.x;
    s1 += v.y;
  }
  outb[(size_t)wid * 128 + j0]     = fmaxf(s0, 0.f);
  outb[(size_t)wid * 128 + j0 + 1] = fmaxf(s1, 0.f);
}

// ------------------------------ molecule conv ------------------------------

__global__ void k_conv_mol(const float* __restrict__ hsm, const float* __restrict__ asrc,
                           const float* __restrict__ adg, const float* __restrict__ bm,
                           const int* __restrict__ goff, float* __restrict__ hout, int G) {
  int wid = (blockIdx.x * blockDim.x + threadIdx.x) >> 6;
  if (wid >= G) return;
  int lane = threadIdx.x & 63;
  int j0 = lane * 2;
  float adn = adg[wid];
  float m = -INFINITY, s = 0.f, acc0 = 0.f, acc1 = 0.f;
  int n0 = goff[wid], n1 = goff[wid + 1];
  for (int n = n0; n < n1; ++n) {
    float logit = leaky01(asrc[n] + adn);
    float mn = fmaxf(m, logit);
    float sc = expf(m - mn);
    float p = expf(logit - mn);
    float2 hv = *(const float2*)(hsm + (size_t)n * 128 + j0);
    s = s * sc + p;
    acc0 = acc0 * sc + p * hv.x;
    acc1 = acc1 * sc + p * hv.y;
    m = mn;
  }
  float r = 1.f / (s + 1e-16f);
  hout[(size_t)wid * 128 + j0]     = eluf(acc0 * r + bm[j0]);
  hout[(size_t)wid * 128 + j0 + 1] = eluf(acc1 * r + bm[j0 + 1]);
}

// ------------------------------ fused GRU ----------------------------------
// out = relu(gru(inp, hid)). Wi/Wh: [384,128] (x @ W.T). 16 rows/block.

__launch_bounds__(256)
__global__ void k_gru(const float* __restrict__ inp, const float* __restrict__ hid,
                      const float* __restrict__ Wi, const float* __restrict__ bi,
                      const float* __restrict__ Wh, const float* __restrict__ bh,
                      float* __restrict__ out, int M) {
  __shared__ float inS[16][132];
  __shared__ float hidS[16][132];
  int t = threadIdx.x;
  int m0 = blockIdx.x * 16;
  #pragma unroll
  for (int i = 0; i < 2; ++i) {
    int f = t + i * 256;
    int row = f >> 5, kf = f & 31;
    int gr = m0 + row;
    float4 vi = make_float4(0.f, 0.f, 0.f, 0.f), vh = vi;
    if (gr < M) {
      vi = *(const float4*)(inp + (size_t)gr * 128 + kf * 4);
      vh = *(const float4*)(hid + (size_t)gr * 128 + kf * 4);
    }
    *(float4*)(&inS[row][kf * 4]) = vi;
    *(float4*)(&hidS[row][kf * 4]) = vh;
  }
  __syncthreads();

  int j = t & 127;
  int rbase = (t >> 7) * 8;

  float aI[8], aH[8], rv[8], zv[8];
  auto dot2 = [&](int c) {
    const float* wi = Wi + (size_t)(c * 128 + j) * 128;
    const float* wh = Wh + (size_t)(c * 128 + j) * 128;
    #pragma unroll
    for (int r = 0; r < 8; ++r) { aI[r] = 0.f; aH[r] = 0.f; }
    for (int k = 0; k < 128; k += 4) {
      float4 w4 = *(const float4*)(wi + k);
      float4 v4 = *(const float4*)(wh + k);
      #pragma unroll
      for (int r = 0; r < 8; ++r) {
        float4 x4 = *(const float4*)(&inS[rbase + r][k]);
        float4 h4 = *(const float4*)(&hidS[rbase + r][k]);
        aI[r] += x4.x * w4.x + x4.y * w4.y + x4.z * w4.z + x4.w * w4.w;
        aH[r] += h4.x * v4.x + h4.y * v4.y + h4.z * v4.z + h4.w * v4.w;
      }
    }
  };

  dot2(0);
  {
    float bI = bi[j], bH = bh[j];
    #pragma unroll
    for (int r = 0; r < 8; ++r) rv[r] = sigmf(aI[r] + bI + aH[r] + bH);
  }
  dot2(1);
  {
    float bI = bi[128 + j], bH = bh[128 + j];
    #pragma unroll
    for (int r = 0; r < 8; ++r) zv[r] = sigmf(aI[r] + bI + aH[r] + bH);
  }
  dot2(2);
  {
    float bI = bi[256 + j], bH = bh[256 + j];
    #pragma unroll
    for (int r = 0; r < 8; ++r) {
      float nv = tanhf(aI[r] + bI + rv[r] * (aH[r] + bH));
      float hv = hidS[rbase + r][j];
      float o = (1.f - zv[r]) * nv + zv[r] * hv;
      int gr = m0 + rbase + r;
      if (gr < M) out[(size_t)gr * 128 + j] = fmaxf(o, 0.f);
    }
  }
}

// ------------------------------ final head ---------------------------------

__global__ void k_final(const float* __restrict__ outb, const float* __restrict__ W2,
                        const float* __restrict__ b2, const float* __restrict__ Wp1,
                        const float* __restrict__ bp1, const float* __restrict__ Wp2,
                        const float* __restrict__ bp2, float* __restrict__ y, int G) {
  int g = blockIdx.x * 256 + threadIdx.x;
  if (g >= G) return;
  const float* o = outb + (size_t)g * 128;
  float s0 = b2[0], s1 = b2[1];
  for (int k = 0; k < 128; ++k) {
    float v = o[k];
    s0 += v * W2[2 * k];
    s1 += v * W2[2 * k + 1];
  }
  float p = s0 * Wp1[0] + s1 * Wp1[1] + bp1[0];
  p = fmaxf(p, 0.f);
  y[g] = p * Wp2[0] + bp2[0];
}

// ---------------------------------------------------------------------------

extern "C" void kernel_launch(void* const* d_in, const int* in_sizes, int n_in,
                              void* d_out, int out_size, void* d_ws, size_t ws_size,
                              hipStream_t stream) {
  const int N = 50000, E = 800000, G = 1000, NL = 4;

  const float* x_in  = (const float*)d_in[0];
  const int*   ei    = (const int*)  d_in[1];
  const int*   batch = (const int*)  d_in[2];
  const float* eattr = (const float*)d_in[3];
  const float* W1    = (const float*)d_in[4];
  const float* b1    = (const float*)d_in[5];
  const float* Wg1   = (const float*)d_in[6];
  const float* attL  = (const float*)d_in[7];
  const float* attR  = (const float*)d_in[8];
  const float* Wg2   = (const float*)d_in[9];
  const float* bg    = (const float*)d_in[10];
  const float* gWi0  = (const float*)d_in[11];
  const float* gWh0  = (const float*)d_in[12];
  const float* gbi0  = (const float*)d_in[13];
  const float* gbh0  = (const float*)d_in[14];
  const float* Wc    = (const float*)d_in[15];
  const float* aS    = (const float*)d_in[16];
  const float* aD    = (const float*)d_in[17];
  const float* bc    = (const float*)d_in[18];
  const float* gWi   = (const float*)d_in[19];
  const float* gWh   = (const float*)d_in[20];
  const float* gbi   = (const float*)d_in[21];
  const float* gbh   = (const float*)d_in[22];
  const float* Wm    = (const float*)d_in[23];
  const float* aSm   = (const float*)d_in[24];
  const float* aDm   = (const float*)d_in[25];
  const float* bm    = (const float*)d_in[26];
  const float* mWi   = (const float*)d_in[27];
  const float* mWh   = (const float*)d_in[28];
  const float* mbi   = (const float*)d_in[29];
  const float* mbh   = (const float*)d_in[30];
  const float* W2    = (const float*)d_in[31];
  const float* b2    = (const float*)d_in[32];
  const float* Wp1   = (const float*)d_in[33];
  const float* bp1   = (const float*)d_in[34];
  const float* Wp2   = (const float*)d_in[35];
  const float* bp2   = (const float*)d_in[36];

  char* base = (char*)d_ws;
  size_t o = 0;
  auto alloc = [&](size_t bytes) -> char* {
    char* p = base + o;
    o += (bytes + 255) & ~(size_t)255;
    return p;
  };
  float* X    = (float*)alloc((size_t)N * 128 * 4);
  float* Hb   = (float*)alloc((size_t)N * 128 * 4);
  float* S    = (float*)alloc((size_t)N * 128 * 4);
  float* AGG  = (float*)alloc((size_t)N * 128 * 4);
  float* sc1  = (float*)alloc((size_t)N * 4);
  float* sc2  = (float*)alloc((size_t)N * 4);
  float* asrc = (float*)alloc((size_t)N * 4);
  float* OutB = (float*)alloc((size_t)G * 128 * 4);
  float* Hm   = (float*)alloc((size_t)G * 128 * 4);
  float* oWm  = (float*)alloc((size_t)G * 128 * 4);
  float* adg  = (float*)alloc((size_t)G * 4);
  int*   deg  = (int*)alloc((size_t)N * 4);
  int*   off  = (int*)alloc((size_t)(N + 1) * 4);
  int*   cur  = (int*)alloc((size_t)N * 4);
  int*   csrc = (int*)alloc((size_t)E * 4);
  int*   ceid = (int*)alloc((size_t)E * 4);
  int*   degG = (int*)alloc((size_t)G * 4);
  int*   goff = (int*)alloc((size_t)(G + 1) * 4);
  int*   bs   = (int*)alloc(256 * 4);
  if (o > ws_size) return;  // workspace too small: fail visibly (output stays poisoned)

  hipMemsetAsync(deg, 0, (size_t)N * 4, stream);
  hipMemsetAsync(cur, 0, (size_t)N * 4, stream);
  hipMemsetAsync(degG, 0, (size_t)G * 4, stream);
  hipMemsetAsync(off, 0, 4, stream);
  hipMemsetAsync(goff, 0, 4, stream);

  int nb1 = (N + 255) / 256;
  int nbG = (G + 255) / 256;
  k_hist<<<(E + 255) / 256, 256, 0, stream>>>(ei + E, deg, E);
  k_scan1<<<nb1, 256, 0, stream>>>(deg, off + 1, bs, N);
  k_scan2<<<1, 256, 0, stream>>>(bs, nb1);
  k_scan3<<<nb1, 256, 0, stream>>>(off + 1, bs, N);
  k_scatter<<<(E + 255) / 256, 256, 0, stream>>>(ei, off, cur, csrc, ceid, E);
  k_hist<<<(N + 255) / 256, 256, 0, stream>>>(batch, degG, N);
  k_scan1<<<nbG, 256, 0, stream>>>(degG, goff + 1, bs, G);
  k_scan2<<<1, 256, 0, stream>>>(bs, nbG);
  k_scan3<<<nbG, 256, 0, stream>>>(goff + 1, bs, G);

  auto gemm = [&](const float* A, const float* W, const float* bias, float* C,
                  int M, int Nout, int wTrans, int act) {
    dim3 grid((M + 63) / 64, Nout / 32);
    k_gemm<<<grid, 256, 0, stream>>>(A, W, bias, C, M, Nout, wTrans, act);
  };

  // lin1 + leaky
  gemm(x_in, W1, b1, X, N, 128, 0, 1);

  // --- GATEConv ---
  gemm(X, Wg1, nullptr, S, N, 128, 0, 0);                       // xg = X @ Wg1[:128]
  k_matvec2<<<(N + 3) / 4, 256, 0, stream>>>(X, attR, nullptr, sc1, nullptr, N);
  k_conv_gate<<<(N + 3) / 4, 256, 0, stream>>>(S, Wg1 + 128 * 128, attL, sc1, eattr,
                                               off, csrc, ceid, AGG, N);
  gemm(AGG, Wg2, bg, Hb, N, 128, 0, 3);                         // elu(agg@Wg2+bg)
  k_gru<<<(N + 15) / 16, 256, 0, stream>>>(Hb, X, gWi0, gbi0, gWh0, gbh0, X, N);

  // --- GATConv layers ---
  for (int l = 0; l < NL - 1; ++l) {
    gemm(X, Wc + (size_t)l * 128 * 128, nullptr, S, N, 128, 0, 0);   // hs
    k_matvec2<<<(N + 3) / 4, 256, 0, stream>>>(S, aS + l * 128, aD + l * 128, sc1, sc2, N);
    k_conv_gat<<<(N + 3) / 4, 256, 0, stream>>>(S, sc1, sc2, bc + l * 128, off, csrc, Hb, N);
    k_gru<<<(N + 15) / 16, 256, 0, stream>>>(Hb, X, gWi + (size_t)l * 384 * 128, gbi + l * 384,
                                             gWh + (size_t)l * 384 * 128, gbh + l * 384, X, N);
  }

  // --- molecule phase ---
  k_pool<<<(G + 3) / 4, 256, 0, stream>>>(X, goff, OutB, G);
  gemm(X, Wm, nullptr, S, N, 128, 0, 0);                         // hsm
  k_matvec2<<<(N + 3) / 4, 256, 0, stream>>>(S, aSm, nullptr, asrc, nullptr, N);
  for (int t = 0; t < 2; ++t) {
    gemm(OutB, Wm, nullptr, oWm, G, 128, 0, 0);
    k_matvec2<<<(G + 3) / 4, 256, 0, stream>>>(oWm, aDm, nullptr, adg, nullptr, G);
    k_conv_mol<<<(G + 3) / 4, 256, 0, stream>>>(S, asrc, adg, bm, goff, Hm, G);
    k_gru<<<(G + 15) / 16, 256, 0, stream>>>(Hm, OutB, mWi, mbi, mWh, mbh, OutB, G);
  }

  k_final<<<(G + 255) / 256, 256, 0, stream>>>(OutB, W2, b2, Wp1, bp1, Wp2, bp2,
                                               (float*)d_out, G);
}